// Round 6
// baseline (511.464 us; speedup 1.0000x reference)
//
#include <hip/hip_runtime.h>
#include <hip/hip_bf16.h>
#include <math.h>

#define HIDDEN 1024
#define HEADS 16
#define DK 64
#define BATCH 2
#define SLEN 2048

typedef __attribute__((ext_vector_type(8))) short short8v;
typedef __attribute__((ext_vector_type(4))) float f32x4;

// --- truncation-based split: x = hi + lo + O(2^-17 |x|). 3-4 VALU ops. ---
__device__ __forceinline__ float bf_f(unsigned short h) {
  unsigned u = ((unsigned)h) << 16;
  return __builtin_bit_cast(float, u);
}
__device__ __forceinline__ void split_t(float x, unsigned short& hi,
                                        unsigned short& lo) {
  unsigned xu = __builtin_bit_cast(unsigned, x);
  float r = x - __builtin_bit_cast(float, xu & 0xffff0000u);
  hi = (unsigned short)(xu >> 16);
  lo = (unsigned short)(__builtin_bit_cast(unsigned, r) >> 16);
}
// packed (hi | lo<<16) in one u32 via a single v_perm
__device__ __forceinline__ unsigned pack_hl_t(float x) {
  unsigned xu = __builtin_bit_cast(unsigned, x);
  float r = x - __builtin_bit_cast(float, xu & 0xffff0000u);
  unsigned ru = __builtin_bit_cast(unsigned, r);
  return __builtin_amdgcn_perm(ru, xu, 0x07060302u);  // {x.b2,x.b3,r.b2,r.b3}
}

// unpack 8 packed u32 (hi|lo per element, k ascending) into hi or lo short8v
__device__ __forceinline__ short8v unpack8(const uint4& a0, const uint4& a1,
                                           unsigned sel) {
  uint4 r;
  r.x = __builtin_amdgcn_perm(a0.y, a0.x, sel);
  r.y = __builtin_amdgcn_perm(a0.w, a0.z, sel);
  r.z = __builtin_amdgcn_perm(a1.y, a1.x, sel);
  r.w = __builtin_amdgcn_perm(a1.w, a1.z, sel);
  return __builtin_bit_cast(short8v, r);
}
#define SEL_HI 0x05040100u
#define SEL_LO 0x07060302u

#define GLB_US(p) ((const __attribute__((address_space(1))) unsigned short*)(p))
#define LDS_US(p) ((__attribute__((address_space(3))) unsigned short*)(p))

#define QSCALE 0.18033688011112042f  /* 1/sqrt(64) * log2(e) */

// ---------------------------------------------------------------------------
// mask [B][1][S][S] int -> bitmask u64 per (row, 64-col tile). 1MB, L2-resident.
// ---------------------------------------------------------------------------
__global__ __launch_bounds__(256) void mask_bits_kernel(
    const int* __restrict__ mask, unsigned long long* __restrict__ Mb)
{
  const int row = blockIdx.x * 4 + (threadIdx.x >> 6);  // 0..B*S-1
  const int lane = threadIdx.x & 63;
  const int* mr = mask + (size_t)row * SLEN;
#pragma unroll
  for (int t = 0; t < 32; ++t) {
    int m = mr[t * 64 + lane];
    unsigned long long bits = __ballot(m != 0);
    if (lane == 0) Mb[(size_t)row * 32 + t] = bits;
  }
}

// ---------------------------------------------------------------------------
// pack fp32 -> separate bf16 hi/lo planes (truncation split)
// ---------------------------------------------------------------------------
__global__ __launch_bounds__(256) void pack_act_kernel(
    const float* __restrict__ src, unsigned short* __restrict__ hi,
    unsigned short* __restrict__ lo, int n4)
{
  int stride = gridDim.x * blockDim.x;
  for (int i = blockIdx.x * blockDim.x + threadIdx.x; i < n4; i += stride) {
    float4 v = ((const float4*)src)[i];
    ushort4 H, L;
    split_t(v.x, H.x, L.x); split_t(v.y, H.y, L.y);
    split_t(v.z, H.z, L.z); split_t(v.w, H.w, L.w);
    *(ushort4*)(hi + (size_t)i * 4) = H;
    *(ushort4*)(lo + (size_t)i * 4) = L;
  }
}

// ---------------------------------------------------------------------------
// pack + transpose weight: W[k][n] fp32 -> Wt hi/lo planes [n][k] bf16
// ---------------------------------------------------------------------------
__global__ __launch_bounds__(256) void pack_wT_kernel(
    const float* __restrict__ W, unsigned short* __restrict__ Whi,
    unsigned short* __restrict__ Wlo)
{
  __shared__ float T[64][65];
  const int t = threadIdx.x;
  const int bk = blockIdx.x >> 4, bn = blockIdx.x & 15;
#pragma unroll
  for (int i = 0; i < 4; ++i) {
    int k = (t >> 4) + i * 16, n = (t & 15) * 4;
    float4 v = *(const float4*)(W + (size_t)(bk * 64 + k) * HIDDEN + bn * 64 + n);
    T[k][n + 0] = v.x; T[k][n + 1] = v.y; T[k][n + 2] = v.z; T[k][n + 3] = v.w;
  }
  __syncthreads();
  const int nl = t & 63, kc = (t >> 6) * 16;
#pragma unroll
  for (int i = 0; i < 4; ++i) {
    ushort4 H, L;
    split_t(T[kc + i * 4 + 0][nl], H.x, L.x);
    split_t(T[kc + i * 4 + 1][nl], H.y, L.y);
    split_t(T[kc + i * 4 + 2][nl], H.z, L.z);
    split_t(T[kc + i * 4 + 3][nl], H.w, L.w);
    size_t base = (size_t)(bn * 64 + nl) * HIDDEN + bk * 64 + kc + i * 4;
    *(ushort4*)(Whi + base) = H;
    *(ushort4*)(Wlo + base) = L;
  }
}

// ---------------------------------------------------------------------------
// Split-precision bf16 MFMA GEMM, hi/lo planes. 64x64 tile, BK=32, 4 waves,
// double-buffered LDS (2-phase: stage next || compute cur, 1 barrier/K-step).
// L2-blocking swizzle: per-XCD m-stripe (2MB, L2-resident), bm fastest so the
// B column-panel (256KB) stays hot. oscale folds softmax scale into Q.
// mode 0: Yf[m][n] fp32.  mode 1: Yhi/Ylo [bh][s][d].  mode 2: [bh*64+d][s].
// ---------------------------------------------------------------------------
__global__ __launch_bounds__(256) void gemm_sp_kernel(
    const unsigned short* __restrict__ Ahi, const unsigned short* __restrict__ Alo,
    const unsigned short* __restrict__ Bthi, const unsigned short* __restrict__ Btlo,
    const float* __restrict__ bias, float oscale,
    unsigned short* __restrict__ Yhi, unsigned short* __restrict__ Ylo,
    float* __restrict__ Yf, int mode)
{
  __shared__ __align__(16) unsigned short lds[2][4][64 * 32];  // 32KB

  const int tid = threadIdx.x;
  const int xcd = blockIdx.x & 7;
  const int idx = blockIdx.x >> 3;        // 0..127
  const int bm = xcd * 8 + (idx & 7);     // per-XCD m-stripe, bm fastest
  const int bn = idx >> 3;                // 0..15
  const int m0 = bm * 64, n0 = bn * 64;
  const int w = tid >> 6, lane = tid & 63;
  const int wm = w >> 1, wn = w & 1;
  const int g = lane >> 4, qi = lane & 15;

  const int tr = tid >> 2;
  const int tc = (((tid & 3) ^ ((tr >> 2) & 3)) << 3);
  const int dofs = tid * 8;  // linear LDS dest (ushort units)

  f32x4 acc[2][2];
#pragma unroll
  for (int mt = 0; mt < 2; ++mt)
#pragma unroll
    for (int nt = 0; nt < 2; ++nt) acc[mt][nt] = (f32x4){0.f, 0.f, 0.f, 0.f};

  auto stage = [&](int buf, int k0) {
    size_t ga = (size_t)(m0 + tr) * HIDDEN + k0 + tc;
    size_t gb = (size_t)(n0 + tr) * HIDDEN + k0 + tc;
    __builtin_amdgcn_global_load_lds(GLB_US(Ahi + ga), LDS_US(&lds[buf][0][dofs]), 16, 0, 0);
    __builtin_amdgcn_global_load_lds(GLB_US(Alo + ga), LDS_US(&lds[buf][1][dofs]), 16, 0, 0);
    __builtin_amdgcn_global_load_lds(GLB_US(Bthi + gb), LDS_US(&lds[buf][2][dofs]), 16, 0, 0);
    __builtin_amdgcn_global_load_lds(GLB_US(Btlo + gb), LDS_US(&lds[buf][3][dofs]), 16, 0, 0);
  };

  auto compute = [&](int buf) {
    short8v a_h[2], a_l[2], b_h[2], b_l[2];
#pragma unroll
    for (int mt = 0; mt < 2; ++mt) {
      int R = wm * 32 + mt * 16 + qi;
      int cofs = R * 32 + ((g ^ ((R >> 2) & 3)) << 3);
      a_h[mt] = *(const short8v*)&lds[buf][0][cofs];
      a_l[mt] = *(const short8v*)&lds[buf][1][cofs];
    }
#pragma unroll
    for (int nt = 0; nt < 2; ++nt) {
      int R = wn * 32 + nt * 16 + qi;
      int cofs = R * 32 + ((g ^ ((R >> 2) & 3)) << 3);
      b_h[nt] = *(const short8v*)&lds[buf][2][cofs];
      b_l[nt] = *(const short8v*)&lds[buf][3][cofs];
    }
#pragma unroll
    for (int nt = 0; nt < 2; ++nt)
#pragma unroll
      for (int mt = 0; mt < 2; ++mt) {
        acc[mt][nt] = __builtin_amdgcn_mfma_f32_16x16x32_bf16(a_h[mt], b_h[nt], acc[mt][nt], 0, 0, 0);
        acc[mt][nt] = __builtin_amdgcn_mfma_f32_16x16x32_bf16(a_l[mt], b_h[nt], acc[mt][nt], 0, 0, 0);
        acc[mt][nt] = __builtin_amdgcn_mfma_f32_16x16x32_bf16(a_h[mt], b_l[nt], acc[mt][nt], 0, 0, 0);
      }
  };

  stage(0, 0);
  __syncthreads();
  for (int t = 0; t < 31; ++t) {
    stage((t + 1) & 1, (t + 1) * 32);  // async loads into other buffer
    compute(t & 1);
    __syncthreads();                   // drains vmcnt; protects buffer reuse
  }
  compute(1);

  // epilogue
#pragma unroll
  for (int nt = 0; nt < 2; ++nt) {
    int n = n0 + wn * 32 + nt * 16 + qi;
    float bv = bias[n];
#pragma unroll
    for (int mt = 0; mt < 2; ++mt) {
#pragma unroll
      for (int r = 0; r < 4; ++r) {
        int m = m0 + wm * 32 + mt * 16 + g * 4 + r;
        float val = (acc[mt][nt][r] + bv) * oscale;
        if (mode == 0) {
          Yf[(size_t)m * HIDDEN + n] = val;
        } else {
          int s = m & (SLEN - 1);
          int bh_ = (m >> 11) * HEADS + (n >> 6);
          int d = n & 63;
          unsigned short hi, lo;
          split_t(val, hi, lo);
          size_t base = (mode == 1) ? (((size_t)bh_ * SLEN + s) << 6) + d
                                    : ((size_t)(bh_ * DK + d)) * SLEN + s;
          Yhi[base] = hi;
          Ylo[base] = lo;
        }
      }
    }
  }
}

// ---------------------------------------------------------------------------
// MFMA flash attention, swapped QK^T, log2-domain softmax (Q pre-scaled by
// 1/8*log2e at projection; exp2f = native v_exp). Mask via u64 bitmask.
// Defer-max (THR=11.5 in log2 domain). P packed u32 in K-region-aliased LDS.
// ---------------------------------------------------------------------------
__global__ __launch_bounds__(256) void attn_mfma_kernel(
    const unsigned short* __restrict__ Qhi, const unsigned short* __restrict__ Qlo,
    const unsigned short* __restrict__ Khi, const unsigned short* __restrict__ Klo,
    const unsigned short* __restrict__ Vthi, const unsigned short* __restrict__ Vtlo,
    const unsigned long long* __restrict__ Mb,
    unsigned short* __restrict__ XaHi, unsigned short* __restrict__ XaLo)
{
  __shared__ __align__(16) unsigned char smem[32768];
  unsigned short* Ks_hi = (unsigned short*)smem;             // [64][64] 8KB
  unsigned short* Ks_lo = (unsigned short*)(smem + 8192);
  unsigned short* Vs_hi = (unsigned short*)(smem + 16384);
  unsigned short* Vs_lo = (unsigned short*)(smem + 24576);

  const int tid = threadIdx.x;
  const int bx = blockIdx.x;
  const int lb = (bx & 7) * 128 + (bx >> 3);  // XCD swizzle: bh-stripe per XCD
  const int qt = lb & 31;
  const int bh = lb >> 5;
  const int b = bh >> 4, h = bh & 15;
  const int w = tid >> 6, lane = tid & 63;
  const int g = lane >> 4, qi = lane & 15;
  const int qbase = qt * 64 + w * 16;

  unsigned* Pw = (unsigned*)(smem + w * 4096);  // wave-private, aliases K region

  short8v qh[2], ql[2];
  {
    const unsigned short* qr_hi = Qhi + ((size_t)bh * SLEN + qbase + qi) * DK;
    const unsigned short* qr_lo = Qlo + ((size_t)bh * SLEN + qbase + qi) * DK;
    qh[0] = *(const short8v*)(qr_hi + g * 8);
    qh[1] = *(const short8v*)(qr_hi + 32 + g * 8);
    ql[0] = *(const short8v*)(qr_lo + g * 8);
    ql[1] = *(const short8v*)(qr_lo + 32 + g * 8);
  }

  f32x4 o[4];
#pragma unroll
  for (int dt = 0; dt < 4; ++dt) o[dt] = (f32x4){0.f, 0.f, 0.f, 0.f};
  float m_run = -1e30f, l_run = 0.f;

  const unsigned long long* mrow = Mb + ((size_t)b * SLEN + qbase + qi) * 32;

  for (int k0 = 0; k0 < SLEN; k0 += 64) {
    __syncthreads();
#pragma unroll
    for (int i = 0; i < 2; ++i) {
      int rloc = w * 16 + i * 8 + (lane >> 3);
      int col = ((lane & 7) * 8) ^ ((rloc & 7) << 3);
      size_t gk = ((size_t)bh * SLEN + k0 + rloc) * 64 + col;
      size_t gv = ((size_t)(bh * 64 + rloc)) * SLEN + k0 + col;
      int dofs = rloc * 64 + (lane & 7) * 8;  // linear dest
      __builtin_amdgcn_global_load_lds(GLB_US(Khi + gk), LDS_US(Ks_hi + dofs), 16, 0, 0);
      __builtin_amdgcn_global_load_lds(GLB_US(Klo + gk), LDS_US(Ks_lo + dofs), 16, 0, 0);
      __builtin_amdgcn_global_load_lds(GLB_US(Vthi + gv), LDS_US(Vs_hi + dofs), 16, 0, 0);
      __builtin_amdgcn_global_load_lds(GLB_US(Vtlo + gv), LDS_US(Vs_lo + dofs), 16, 0, 0);
    }
    __syncthreads();

    // QK^T swapped: S^T[k][q]; lane (g,qi) holds k = ks*16+g*4+r for q = qi
    f32x4 sf[4];
#pragma unroll
    for (int ks = 0; ks < 4; ++ks) {
      int krow = ks * 16 + qi;
      int cswz = (krow & 7) << 3;
      short8v kh0 = *(const short8v*)&Ks_hi[krow * 64 + ((g * 8) ^ cswz)];
      short8v kh1 = *(const short8v*)&Ks_hi[krow * 64 + ((32 + g * 8) ^ cswz)];
      short8v kl0 = *(const short8v*)&Ks_lo[krow * 64 + ((g * 8) ^ cswz)];
      short8v kl1 = *(const short8v*)&Ks_lo[krow * 64 + ((32 + g * 8) ^ cswz)];
      f32x4 s = {0.f, 0.f, 0.f, 0.f};
      s = __builtin_amdgcn_mfma_f32_16x16x32_bf16(kh0, qh[0], s, 0, 0, 0);
      s = __builtin_amdgcn_mfma_f32_16x16x32_bf16(kh1, qh[1], s, 0, 0, 0);
      s = __builtin_amdgcn_mfma_f32_16x16x32_bf16(kh0, ql[0], s, 0, 0, 0);
      s = __builtin_amdgcn_mfma_f32_16x16x32_bf16(kh1, ql[1], s, 0, 0, 0);
      s = __builtin_amdgcn_mfma_f32_16x16x32_bf16(kl0, qh[0], s, 0, 0, 0);
      s = __builtin_amdgcn_mfma_f32_16x16x32_bf16(kl1, qh[1], s, 0, 0, 0);
      sf[ks] = s;
    }
    __syncthreads();  // all waves done reading K region -> P may overwrite it

    // mask + per-lane softmax stats (log2 domain) for q-row qi
    unsigned long long mw = mrow[k0 >> 6];
    unsigned s0 = ((unsigned)mw) >> (g * 4);
    unsigned s1 = ((unsigned)(mw >> 32)) >> (g * 4);
    float sv[4][4];
    float rowmax = -INFINITY;
#pragma unroll
    for (int ks = 0; ks < 4; ++ks) {
      unsigned sel = (ks < 2) ? s0 : s1;
#pragma unroll
      for (int r = 0; r < 4; ++r) {
        float x = sf[ks][r];
        sv[ks][r] = ((sel >> (((ks & 1) << 4) + r)) & 1) ? x : -INFINITY;
        rowmax = fmaxf(rowmax, sv[ks][r]);
      }
    }
    rowmax = fmaxf(rowmax, __shfl_xor(rowmax, 16));
    rowmax = fmaxf(rowmax, __shfl_xor(rowmax, 32));

    if (__any(rowmax > m_run + 11.5f)) {  // defer-max, log2 domain
      float mnew = fmaxf(m_run, rowmax);
      float scale = exp2f(m_run - mnew);
      l_run *= scale;
#pragma unroll
      for (int r = 0; r < 4; ++r) {
        float sc = __shfl(scale, g * 4 + r);  // O rows are q = g*4+r
        o[0][r] *= sc; o[1][r] *= sc; o[2][r] *= sc; o[3][r] *= sc;
      }
      m_run = mnew;
    }

    // P = exp2(S - m), packed hi|lo, into [k][16] swizzled LDS
    float lsum = 0.f;
#pragma unroll
    for (int ks = 0; ks < 4; ++ks)
#pragma unroll
      for (int r = 0; r < 4; ++r) {
        float pv = exp2f(sv[ks][r] - m_run);
        lsum += pv;
        int k = ks * 16 + g * 4 + r;
        int wa = (k << 4) + qi;
        wa ^= ((wa >> 7) & 1) << 4;
        Pw[wa] = pack_hl_t(pv);
      }
    lsum += __shfl_xor(lsum, 16);
    lsum += __shfl_xor(lsum, 32);
    l_run += lsum;

    // PV: O += Phi*Vhi + Phi*Vlo + Plo*Vhi
#pragma unroll
    for (int kh = 0; kh < 2; ++kh) {
      unsigned u0, u1, u2, u3, u4, u5, u6, u7;
      {
        int kb = kh * 32 + g * 8;
        int ra;
        ra = ((kb + 0) << 4) + qi; ra ^= ((ra >> 7) & 1) << 4; u0 = Pw[ra];
        ra = ((kb + 1) << 4) + qi; ra ^= ((ra >> 7) & 1) << 4; u1 = Pw[ra];
        ra = ((kb + 2) << 4) + qi; ra ^= ((ra >> 7) & 1) << 4; u2 = Pw[ra];
        ra = ((kb + 3) << 4) + qi; ra ^= ((ra >> 7) & 1) << 4; u3 = Pw[ra];
        ra = ((kb + 4) << 4) + qi; ra ^= ((ra >> 7) & 1) << 4; u4 = Pw[ra];
        ra = ((kb + 5) << 4) + qi; ra ^= ((ra >> 7) & 1) << 4; u5 = Pw[ra];
        ra = ((kb + 6) << 4) + qi; ra ^= ((ra >> 7) & 1) << 4; u6 = Pw[ra];
        ra = ((kb + 7) << 4) + qi; ra ^= ((ra >> 7) & 1) << 4; u7 = Pw[ra];
      }
      uint4 a0 = {u0, u1, u2, u3}, a1 = {u4, u5, u6, u7};
      short8v phi = unpack8(a0, a1, SEL_HI);
      short8v plo = unpack8(a0, a1, SEL_LO);
#pragma unroll
      for (int dt = 0; dt < 4; ++dt) {
        int drow = dt * 16 + qi;
        int vcol = (kh * 32 + g * 8) ^ ((drow & 7) << 3);
        short8v vh = *(const short8v*)&Vs_hi[drow * 64 + vcol];
        short8v vl = *(const short8v*)&Vs_lo[drow * 64 + vcol];
        o[dt] = __builtin_amdgcn_mfma_f32_16x16x32_bf16(phi, vh, o[dt], 0, 0, 0);
        o[dt] = __builtin_amdgcn_mfma_f32_16x16x32_bf16(phi, vl, o[dt], 0, 0, 0);
        o[dt] = __builtin_amdgcn_mfma_f32_16x16x32_bf16(plo, vh, o[dt], 0, 0, 0);
      }
    }
  }

  // normalize + write Xa hi/lo planes [b*S+s][h*64+d]
#pragma unroll
  for (int r = 0; r < 4; ++r) {
    float lr = __shfl(l_run, g * 4 + r);
    float inv = lr > 0.f ? 1.f / lr : 0.f;
    size_t rowa = ((size_t)(b * SLEN) + qbase + g * 4 + r) * HIDDEN + h * DK;
#pragma unroll
    for (int dt = 0; dt < 4; ++dt) {
      float val = o[dt][r] * inv;
      unsigned short hi, lo;
      split_t(val, hi, lo);
      XaHi[rowa + dt * 16 + qi] = hi;
      XaLo[rowa + dt * 16 + qi] = lo;
    }
  }
}

// ---------------------------------------------------------------------------
extern "C" void kernel_launch(void* const* d_in, const int* in_sizes, int n_in,
                              void* d_out, int out_size, void* d_ws, size_t ws_size,
                              hipStream_t stream) {
  const float* q   = (const float*)d_in[0];
  const float* k   = (const float*)d_in[1];
  const float* v   = (const float*)d_in[2];
  const int*  mask = (const int*)d_in[3];
  const float* Wq  = (const float*)d_in[4];
  const float* bq  = (const float*)d_in[5];
  const float* Wk  = (const float*)d_in[6];
  const float* bk  = (const float*)d_in[7];
  const float* Wv  = (const float*)d_in[8];
  const float* bv  = (const float*)d_in[9];
  const float* Wo  = (const float*)d_in[10];
  const float* bo  = (const float*)d_in[11];
  float* out = (float*)d_out;

  const size_t HSZ = (size_t)BATCH * SLEN * HIDDEN;   // 4,194,304 elems
  const size_t WSZ = (size_t)HIDDEN * HIDDEN;         // 1,048,576 elems
  unsigned short* wsu = (unsigned short*)d_ws;
  unsigned short* Qhi = wsu;
  unsigned short* Qlo = wsu + HSZ;
  unsigned short* Khi = wsu + 2 * HSZ;
  unsigned short* Klo = wsu + 3 * HSZ;
  unsigned short* Vthi = wsu + 4 * HSZ;
  unsigned short* Vtlo = wsu + 5 * HSZ;
  unsigned short* Ahi_ = wsu + 6 * HSZ;   // also XaHi (attention output plane)
  unsigned short* Alo_ = wsu + 7 * HSZ;   // also XaLo
  unsigned short* Wthi = wsu + 8 * HSZ;
  unsigned short* Wtlo = wsu + 8 * HSZ + WSZ;
  unsigned long long* Mb = (unsigned long long*)(wsu + 8 * HSZ + 2 * WSZ);

  const int n4 = (int)(HSZ / 4);

  mask_bits_kernel<<<BATCH * SLEN / 4, 256, 0, stream>>>(mask, Mb);

  // Q projection (softmax scale folded in, log2 domain)
  pack_act_kernel<<<1024, 256, 0, stream>>>(q, Ahi_, Alo_, n4);
  pack_wT_kernel<<<256, 256, 0, stream>>>(Wq, Wthi, Wtlo);
  gemm_sp_kernel<<<1024, 256, 0, stream>>>(Ahi_, Alo_, Wthi, Wtlo, bq, QSCALE, Qhi, Qlo, nullptr, 1);
  // K projection
  pack_act_kernel<<<1024, 256, 0, stream>>>(k, Ahi_, Alo_, n4);
  pack_wT_kernel<<<256, 256, 0, stream>>>(Wk, Wthi, Wtlo);
  gemm_sp_kernel<<<1024, 256, 0, stream>>>(Ahi_, Alo_, Wthi, Wtlo, bk, 1.0f, Khi, Klo, nullptr, 1);
  // V projection (transposed output)
  pack_act_kernel<<<1024, 256, 0, stream>>>(v, Ahi_, Alo_, n4);
  pack_wT_kernel<<<256, 256, 0, stream>>>(Wv, Wthi, Wtlo);
  gemm_sp_kernel<<<1024, 256, 0, stream>>>(Ahi_, Alo_, Wthi, Wtlo, bv, 1.0f, Vthi, Vtlo, nullptr, 2);

  // attention -> Xa planes (reuse A-plane buffers)
  attn_mfma_kernel<<<1024, 256, 0, stream>>>(Qhi, Qlo, Khi, Klo, Vthi, Vtlo,
                                             Mb, Ahi_, Alo_);

  // output projection
  pack_wT_kernel<<<256, 256, 0, stream>>>(Wo, Wthi, Wtlo);
  gemm_sp_kernel<<<1024, 256, 0, stream>>>(Ahi_, Alo_, Wthi, Wtlo, bo, 1.0f, nullptr, nullptr, out, 0);
}

// Round 7
// 468.539 us; speedup vs baseline: 1.0916x; 1.0916x over previous
//
#include <hip/hip_runtime.h>
#include <hip/hip_bf16.h>
#include <math.h>

#define HIDDEN 1024
#define HEADS 16
#define DK 64
#define BATCH 2
#define SLEN 2048

typedef __attribute__((ext_vector_type(8))) short short8v;
typedef __attribute__((ext_vector_type(4))) float f32x4;

// --- truncation-based split: x = hi + lo + O(2^-17 |x|). 3-4 VALU ops. ---
__device__ __forceinline__ float bf_f(unsigned short h) {
  unsigned u = ((unsigned)h) << 16;
  return __builtin_bit_cast(float, u);
}
__device__ __forceinline__ void split_t(float x, unsigned short& hi,
                                        unsigned short& lo) {
  unsigned xu = __builtin_bit_cast(unsigned, x);
  float r = x - __builtin_bit_cast(float, xu & 0xffff0000u);
  hi = (unsigned short)(xu >> 16);
  lo = (unsigned short)(__builtin_bit_cast(unsigned, r) >> 16);
}
// packed (hi | lo<<16) in one u32 via a single v_perm
__device__ __forceinline__ unsigned pack_hl_t(float x) {
  unsigned xu = __builtin_bit_cast(unsigned, x);
  float r = x - __builtin_bit_cast(float, xu & 0xffff0000u);
  unsigned ru = __builtin_bit_cast(unsigned, r);
  return __builtin_amdgcn_perm(ru, xu, 0x07060302u);  // {x.b2,x.b3,r.b2,r.b3}
}

// unpack 8 packed u32 (hi|lo per element, k ascending) into hi or lo short8v
__device__ __forceinline__ short8v unpack8(const uint4& a0, const uint4& a1,
                                           unsigned sel) {
  uint4 r;
  r.x = __builtin_amdgcn_perm(a0.y, a0.x, sel);
  r.y = __builtin_amdgcn_perm(a0.w, a0.z, sel);
  r.z = __builtin_amdgcn_perm(a1.y, a1.x, sel);
  r.w = __builtin_amdgcn_perm(a1.w, a1.z, sel);
  return __builtin_bit_cast(short8v, r);
}
#define SEL_HI 0x05040100u
#define SEL_LO 0x07060302u

#define GLB_US(p) ((const __attribute__((address_space(1))) unsigned short*)(p))
#define LDS_US(p) ((__attribute__((address_space(3))) unsigned short*)(p))

#define QSCALE 0.18033688011112042f  /* 1/sqrt(64) * log2(e) */

// ---------------------------------------------------------------------------
// mask [B][1][S][S] int -> bitmask u64 per (row, 64-col tile). 1MB, L2-resident.
// ---------------------------------------------------------------------------
__global__ __launch_bounds__(256) void mask_bits_kernel(
    const int* __restrict__ mask, unsigned long long* __restrict__ Mb)
{
  const int row = blockIdx.x * 4 + (threadIdx.x >> 6);  // 0..B*S-1
  const int lane = threadIdx.x & 63;
  const int* mr = mask + (size_t)row * SLEN;
#pragma unroll
  for (int t = 0; t < 32; ++t) {
    int m = mr[t * 64 + lane];
    unsigned long long bits = __ballot(m != 0);
    if (lane == 0) Mb[(size_t)row * 32 + t] = bits;
  }
}

// ---------------------------------------------------------------------------
// pack fp32 -> separate bf16 hi/lo planes (truncation split)
// ---------------------------------------------------------------------------
__global__ __launch_bounds__(256) void pack_act_kernel(
    const float* __restrict__ src, unsigned short* __restrict__ hi,
    unsigned short* __restrict__ lo, int n4)
{
  int stride = gridDim.x * blockDim.x;
  for (int i = blockIdx.x * blockDim.x + threadIdx.x; i < n4; i += stride) {
    float4 v = ((const float4*)src)[i];
    ushort4 H, L;
    split_t(v.x, H.x, L.x); split_t(v.y, H.y, L.y);
    split_t(v.z, H.z, L.z); split_t(v.w, H.w, L.w);
    *(ushort4*)(hi + (size_t)i * 4) = H;
    *(ushort4*)(lo + (size_t)i * 4) = L;
  }
}

// ---------------------------------------------------------------------------
// pack + transpose weight: W[k][n] fp32 -> Wt hi/lo planes [n][k] bf16
// ---------------------------------------------------------------------------
__global__ __launch_bounds__(256) void pack_wT_kernel(
    const float* __restrict__ W, unsigned short* __restrict__ Whi,
    unsigned short* __restrict__ Wlo)
{
  __shared__ float T[64][65];
  const int t = threadIdx.x;
  const int bk = blockIdx.x >> 4, bn = blockIdx.x & 15;
#pragma unroll
  for (int i = 0; i < 4; ++i) {
    int k = (t >> 4) + i * 16, n = (t & 15) * 4;
    float4 v = *(const float4*)(W + (size_t)(bk * 64 + k) * HIDDEN + bn * 64 + n);
    T[k][n + 0] = v.x; T[k][n + 1] = v.y; T[k][n + 2] = v.z; T[k][n + 3] = v.w;
  }
  __syncthreads();
  const int nl = t & 63, kc = (t >> 6) * 16;
#pragma unroll
  for (int i = 0; i < 4; ++i) {
    ushort4 H, L;
    split_t(T[kc + i * 4 + 0][nl], H.x, L.x);
    split_t(T[kc + i * 4 + 1][nl], H.y, L.y);
    split_t(T[kc + i * 4 + 2][nl], H.z, L.z);
    split_t(T[kc + i * 4 + 3][nl], H.w, L.w);
    size_t base = (size_t)(bn * 64 + nl) * HIDDEN + bk * 64 + kc + i * 4;
    *(ushort4*)(Whi + base) = H;
    *(ushort4*)(Wlo + base) = L;
  }
}

// ---------------------------------------------------------------------------
// Split-precision bf16 MFMA GEMM, hi/lo planes. 64x64 tile, BK=32, 4 waves,
// double-buffered LDS (stage next || compute cur). Frag-read swizzle:
// chunk ^= (row>>1)&3 -> 8 consecutive rows hit 8 distinct bank quads
// (row stride is 64B = half a bank stripe; qi&1 supplies the other bit).
// L2-blocking swizzle: per-XCD m-stripe. oscale folds softmax scale into Q.
// ---------------------------------------------------------------------------
__global__ __launch_bounds__(256) void gemm_sp_kernel(
    const unsigned short* __restrict__ Ahi, const unsigned short* __restrict__ Alo,
    const unsigned short* __restrict__ Bthi, const unsigned short* __restrict__ Btlo,
    const float* __restrict__ bias, float oscale,
    unsigned short* __restrict__ Yhi, unsigned short* __restrict__ Ylo,
    float* __restrict__ Yf, int mode)
{
  __shared__ __align__(16) unsigned short lds[2][4][64 * 32];  // 32KB

  const int tid = threadIdx.x;
  const int xcd = blockIdx.x & 7;
  const int idx = blockIdx.x >> 3;        // 0..127
  const int bm = xcd * 8 + (idx & 7);     // per-XCD m-stripe, bm fastest
  const int bn = idx >> 3;                // 0..15
  const int m0 = bm * 64, n0 = bn * 64;
  const int w = tid >> 6, lane = tid & 63;
  const int wm = w >> 1, wn = w & 1;
  const int g = lane >> 4, qi = lane & 15;

  // staging: thread stages row tid>>2, chunk tid&3; source pre-swizzled with
  // the read-side XOR ((row>>1)&3) so LDS dest stays linear.
  const int tr = tid >> 2;
  const int tc = (((tid & 3) ^ ((tid >> 3) & 3)) << 3);
  const int dofs = tid * 8;  // linear LDS dest (ushort units)

  f32x4 acc[2][2];
#pragma unroll
  for (int mt = 0; mt < 2; ++mt)
#pragma unroll
    for (int nt = 0; nt < 2; ++nt) acc[mt][nt] = (f32x4){0.f, 0.f, 0.f, 0.f};

  auto stage = [&](int buf, int k0) {
    size_t ga = (size_t)(m0 + tr) * HIDDEN + k0 + tc;
    size_t gb = (size_t)(n0 + tr) * HIDDEN + k0 + tc;
    __builtin_amdgcn_global_load_lds(GLB_US(Ahi + ga), LDS_US(&lds[buf][0][dofs]), 16, 0, 0);
    __builtin_amdgcn_global_load_lds(GLB_US(Alo + ga), LDS_US(&lds[buf][1][dofs]), 16, 0, 0);
    __builtin_amdgcn_global_load_lds(GLB_US(Bthi + gb), LDS_US(&lds[buf][2][dofs]), 16, 0, 0);
    __builtin_amdgcn_global_load_lds(GLB_US(Btlo + gb), LDS_US(&lds[buf][3][dofs]), 16, 0, 0);
  };

  auto compute = [&](int buf) {
    short8v a_h[2], a_l[2], b_h[2], b_l[2];
#pragma unroll
    for (int mt = 0; mt < 2; ++mt) {
      int R = wm * 32 + mt * 16 + qi;
      int cofs = R * 32 + ((g ^ ((R >> 1) & 3)) << 3);
      a_h[mt] = *(const short8v*)&lds[buf][0][cofs];
      a_l[mt] = *(const short8v*)&lds[buf][1][cofs];
    }
#pragma unroll
    for (int nt = 0; nt < 2; ++nt) {
      int R = wn * 32 + nt * 16 + qi;
      int cofs = R * 32 + ((g ^ ((R >> 1) & 3)) << 3);
      b_h[nt] = *(const short8v*)&lds[buf][2][cofs];
      b_l[nt] = *(const short8v*)&lds[buf][3][cofs];
    }
#pragma unroll
    for (int nt = 0; nt < 2; ++nt)
#pragma unroll
      for (int mt = 0; mt < 2; ++mt) {
        acc[mt][nt] = __builtin_amdgcn_mfma_f32_16x16x32_bf16(a_h[mt], b_h[nt], acc[mt][nt], 0, 0, 0);
        acc[mt][nt] = __builtin_amdgcn_mfma_f32_16x16x32_bf16(a_l[mt], b_h[nt], acc[mt][nt], 0, 0, 0);
        acc[mt][nt] = __builtin_amdgcn_mfma_f32_16x16x32_bf16(a_h[mt], b_l[nt], acc[mt][nt], 0, 0, 0);
      }
  };

  stage(0, 0);
  __syncthreads();
  for (int t = 0; t < 31; ++t) {
    stage((t + 1) & 1, (t + 1) * 32);  // async loads into other buffer
    compute(t & 1);
    __syncthreads();                   // drains vmcnt; protects buffer reuse
  }
  compute(1);

  // epilogue
#pragma unroll
  for (int nt = 0; nt < 2; ++nt) {
    int n = n0 + wn * 32 + nt * 16 + qi;
    float bv = bias[n];
#pragma unroll
    for (int mt = 0; mt < 2; ++mt) {
#pragma unroll
      for (int r = 0; r < 4; ++r) {
        int m = m0 + wm * 32 + mt * 16 + g * 4 + r;
        float val = (acc[mt][nt][r] + bv) * oscale;
        if (mode == 0) {
          Yf[(size_t)m * HIDDEN + n] = val;
        } else {
          int s = m & (SLEN - 1);
          int bh_ = (m >> 11) * HEADS + (n >> 6);
          int d = n & 63;
          unsigned short hi, lo;
          split_t(val, hi, lo);
          size_t base = (mode == 1) ? (((size_t)bh_ * SLEN + s) << 6) + d
                                    : ((size_t)(bh_ * DK + d)) * SLEN + s;
          Yhi[base] = hi;
          Ylo[base] = lo;
        }
      }
    }
  }
}

// ---------------------------------------------------------------------------
// MFMA flash attention v3: QBLK=128, 8 waves (512 thr), grid 512.
// Each block re-stages K/V once for 128 q-rows (half the L2 traffic of v2).
// Swapped QK^T, log2-domain softmax, u64 bitmask, defer-max THR=11.5.
// P (packed u32) per wave: waves 0-3 alias the K region after the QK^T
// barrier; waves 4-7 use a dedicated 16KB region. LDS total 48KB.
// ---------------------------------------------------------------------------
__global__ __launch_bounds__(512) void attn_mfma_kernel(
    const unsigned short* __restrict__ Qhi, const unsigned short* __restrict__ Qlo,
    const unsigned short* __restrict__ Khi, const unsigned short* __restrict__ Klo,
    const unsigned short* __restrict__ Vthi, const unsigned short* __restrict__ Vtlo,
    const unsigned long long* __restrict__ Mb,
    unsigned short* __restrict__ XaHi, unsigned short* __restrict__ XaLo)
{
  __shared__ __align__(16) unsigned char smem[49152];
  unsigned short* Ks_hi = (unsigned short*)smem;             // [64][64] 8KB
  unsigned short* Ks_lo = (unsigned short*)(smem + 8192);
  unsigned short* Vs_hi = (unsigned short*)(smem + 16384);
  unsigned short* Vs_lo = (unsigned short*)(smem + 24576);
  // P: waves 0-3 alias K region (smem+0..16KB); waves 4-7 at smem+32768.

  const int tid = threadIdx.x;
  const int bx = blockIdx.x;
  const int lb = (bx & 7) * 64 + (bx >> 3);  // XCD swizzle (512 % 8 == 0)
  const int qt = lb & 15;                    // 16 q-tiles of 128
  const int bh = lb >> 4;
  const int b = bh >> 4, h = bh & 15;
  const int w = tid >> 6, lane = tid & 63;
  const int g = lane >> 4, qi = lane & 15;
  const int qbase = qt * 128 + w * 16;

  unsigned* Pw = (unsigned*)(w < 4 ? (smem + w * 4096)
                                   : (smem + 32768 + (w - 4) * 4096));

  short8v qh[2], ql[2];
  {
    const unsigned short* qr_hi = Qhi + ((size_t)bh * SLEN + qbase + qi) * DK;
    const unsigned short* qr_lo = Qlo + ((size_t)bh * SLEN + qbase + qi) * DK;
    qh[0] = *(const short8v*)(qr_hi + g * 8);
    qh[1] = *(const short8v*)(qr_hi + 32 + g * 8);
    ql[0] = *(const short8v*)(qr_lo + g * 8);
    ql[1] = *(const short8v*)(qr_lo + 32 + g * 8);
  }

  f32x4 o[4];
#pragma unroll
  for (int dt = 0; dt < 4; ++dt) o[dt] = (f32x4){0.f, 0.f, 0.f, 0.f};
  float m_run = -1e30f, l_run = 0.f;

  const unsigned long long* mrow = Mb + ((size_t)b * SLEN + qbase + qi) * 32;

  // staging coords: thread stages 16B chunk `tid` of each plane
  const int srow = tid >> 3;                       // 0..63
  const int scol = (((tid & 7) ^ (srow & 7)) << 3);  // pre-swizzled src (ushort)
  const int sdof = tid * 8;                        // linear dest (ushort)

  for (int k0 = 0; k0 < SLEN; k0 += 64) {
    __syncthreads();
    {
      size_t gk = ((size_t)bh * SLEN + k0 + srow) * 64 + scol;
      size_t gv = ((size_t)(bh * 64 + srow)) * SLEN + k0 + scol;
      __builtin_amdgcn_global_load_lds(GLB_US(Khi + gk), LDS_US(Ks_hi + sdof), 16, 0, 0);
      __builtin_amdgcn_global_load_lds(GLB_US(Klo + gk), LDS_US(Ks_lo + sdof), 16, 0, 0);
      __builtin_amdgcn_global_load_lds(GLB_US(Vthi + gv), LDS_US(Vs_hi + sdof), 16, 0, 0);
      __builtin_amdgcn_global_load_lds(GLB_US(Vtlo + gv), LDS_US(Vs_lo + sdof), 16, 0, 0);
    }
    __syncthreads();

    // QK^T swapped: S^T[k][q]; lane (g,qi) holds k = ks*16+g*4+r for q = qi
    f32x4 sf[4];
#pragma unroll
    for (int ks = 0; ks < 4; ++ks) {
      int krow = ks * 16 + qi;
      int cswz = (krow & 7) << 3;
      short8v kh0 = *(const short8v*)&Ks_hi[krow * 64 + ((g * 8) ^ cswz)];
      short8v kh1 = *(const short8v*)&Ks_hi[krow * 64 + ((32 + g * 8) ^ cswz)];
      short8v kl0 = *(const short8v*)&Ks_lo[krow * 64 + ((g * 8) ^ cswz)];
      short8v kl1 = *(const short8v*)&Ks_lo[krow * 64 + ((32 + g * 8) ^ cswz)];
      f32x4 s = {0.f, 0.f, 0.f, 0.f};
      s = __builtin_amdgcn_mfma_f32_16x16x32_bf16(kh0, qh[0], s, 0, 0, 0);
      s = __builtin_amdgcn_mfma_f32_16x16x32_bf16(kh1, qh[1], s, 0, 0, 0);
      s = __builtin_amdgcn_mfma_f32_16x16x32_bf16(kh0, ql[0], s, 0, 0, 0);
      s = __builtin_amdgcn_mfma_f32_16x16x32_bf16(kh1, ql[1], s, 0, 0, 0);
      s = __builtin_amdgcn_mfma_f32_16x16x32_bf16(kl0, qh[0], s, 0, 0, 0);
      s = __builtin_amdgcn_mfma_f32_16x16x32_bf16(kl1, qh[1], s, 0, 0, 0);
      sf[ks] = s;
    }
    __syncthreads();  // all waves done reading K region -> P may overwrite it

    // mask + per-lane softmax stats (log2 domain) for q-row qi
    unsigned long long mw = mrow[k0 >> 6];
    unsigned s0 = ((unsigned)mw) >> (g * 4);
    unsigned s1 = ((unsigned)(mw >> 32)) >> (g * 4);
    float sv[4][4];
    float rowmax = -INFINITY;
#pragma unroll
    for (int ks = 0; ks < 4; ++ks) {
      unsigned sel = (ks < 2) ? s0 : s1;
#pragma unroll
      for (int r = 0; r < 4; ++r) {
        float x = sf[ks][r];
        sv[ks][r] = ((sel >> (((ks & 1) << 4) + r)) & 1) ? x : -INFINITY;
        rowmax = fmaxf(rowmax, sv[ks][r]);
      }
    }
    rowmax = fmaxf(rowmax, __shfl_xor(rowmax, 16));
    rowmax = fmaxf(rowmax, __shfl_xor(rowmax, 32));

    if (__any(rowmax > m_run + 11.5f)) {  // defer-max, log2 domain
      float mnew = fmaxf(m_run, rowmax);
      float scale = exp2f(m_run - mnew);
      l_run *= scale;
#pragma unroll
      for (int r = 0; r < 4; ++r) {
        float sc = __shfl(scale, g * 4 + r);  // O rows are q = g*4+r
        o[0][r] *= sc; o[1][r] *= sc; o[2][r] *= sc; o[3][r] *= sc;
      }
      m_run = mnew;
    }

    // P = exp2(S - m), packed hi|lo, into [k][16] swizzled LDS
    float lsum = 0.f;
#pragma unroll
    for (int ks = 0; ks < 4; ++ks)
#pragma unroll
      for (int r = 0; r < 4; ++r) {
        float pv = exp2f(sv[ks][r] - m_run);
        lsum += pv;
        int k = ks * 16 + g * 4 + r;
        int wa = (k << 4) + qi;
        wa ^= ((wa >> 7) & 1) << 4;
        Pw[wa] = pack_hl_t(pv);
      }
    lsum += __shfl_xor(lsum, 16);
    lsum += __shfl_xor(lsum, 32);
    l_run += lsum;

    // PV: O += Phi*Vhi + Phi*Vlo + Plo*Vhi
#pragma unroll
    for (int kh = 0; kh < 2; ++kh) {
      unsigned u0, u1, u2, u3, u4, u5, u6, u7;
      {
        int kb = kh * 32 + g * 8;
        int ra;
        ra = ((kb + 0) << 4) + qi; ra ^= ((ra >> 7) & 1) << 4; u0 = Pw[ra];
        ra = ((kb + 1) << 4) + qi; ra ^= ((ra >> 7) & 1) << 4; u1 = Pw[ra];
        ra = ((kb + 2) << 4) + qi; ra ^= ((ra >> 7) & 1) << 4; u2 = Pw[ra];
        ra = ((kb + 3) << 4) + qi; ra ^= ((ra >> 7) & 1) << 4; u3 = Pw[ra];
        ra = ((kb + 4) << 4) + qi; ra ^= ((ra >> 7) & 1) << 4; u4 = Pw[ra];
        ra = ((kb + 5) << 4) + qi; ra ^= ((ra >> 7) & 1) << 4; u5 = Pw[ra];
        ra = ((kb + 6) << 4) + qi; ra ^= ((ra >> 7) & 1) << 4; u6 = Pw[ra];
        ra = ((kb + 7) << 4) + qi; ra ^= ((ra >> 7) & 1) << 4; u7 = Pw[ra];
      }
      uint4 a0 = {u0, u1, u2, u3}, a1 = {u4, u5, u6, u7};
      short8v phi = unpack8(a0, a1, SEL_HI);
      short8v plo = unpack8(a0, a1, SEL_LO);
#pragma unroll
      for (int dt = 0; dt < 4; ++dt) {
        int drow = dt * 16 + qi;
        int vcol = (kh * 32 + g * 8) ^ ((drow & 7) << 3);
        short8v vh = *(const short8v*)&Vs_hi[drow * 64 + vcol];
        short8v vl = *(const short8v*)&Vs_lo[drow * 64 + vcol];
        o[dt] = __builtin_amdgcn_mfma_f32_16x16x32_bf16(phi, vh, o[dt], 0, 0, 0);
        o[dt] = __builtin_amdgcn_mfma_f32_16x16x32_bf16(phi, vl, o[dt], 0, 0, 0);
        o[dt] = __builtin_amdgcn_mfma_f32_16x16x32_bf16(plo, vh, o[dt], 0, 0, 0);
      }
    }
  }

  // normalize + write Xa hi/lo planes [b*S+s][h*64+d]
#pragma unroll
  for (int r = 0; r < 4; ++r) {
    float lr = __shfl(l_run, g * 4 + r);
    float inv = lr > 0.f ? 1.f / lr : 0.f;
    size_t rowa = ((size_t)(b * SLEN) + qbase + g * 4 + r) * HIDDEN + h * DK;
#pragma unroll
    for (int dt = 0; dt < 4; ++dt) {
      float val = o[dt][r] * inv;
      unsigned short hi, lo;
      split_t(val, hi, lo);
      XaHi[rowa + dt * 16 + qi] = hi;
      XaLo[rowa + dt * 16 + qi] = lo;
    }
  }
}

// ---------------------------------------------------------------------------
extern "C" void kernel_launch(void* const* d_in, const int* in_sizes, int n_in,
                              void* d_out, int out_size, void* d_ws, size_t ws_size,
                              hipStream_t stream) {
  const float* q   = (const float*)d_in[0];
  const float* k   = (const float*)d_in[1];
  const float* v   = (const float*)d_in[2];
  const int*  mask = (const int*)d_in[3];
  const float* Wq  = (const float*)d_in[4];
  const float* bq  = (const float*)d_in[5];
  const float* Wk  = (const float*)d_in[6];
  const float* bk  = (const float*)d_in[7];
  const float* Wv  = (const float*)d_in[8];
  const float* bv  = (const float*)d_in[9];
  const float* Wo  = (const float*)d_in[10];
  const float* bo  = (const float*)d_in[11];
  float* out = (float*)d_out;

  const size_t HSZ = (size_t)BATCH * SLEN * HIDDEN;   // 4,194,304 elems
  const size_t WSZ = (size_t)HIDDEN * HIDDEN;         // 1,048,576 elems
  unsigned short* wsu = (unsigned short*)d_ws;
  unsigned short* Qhi = wsu;
  unsigned short* Qlo = wsu + HSZ;
  unsigned short* Khi = wsu + 2 * HSZ;
  unsigned short* Klo = wsu + 3 * HSZ;
  unsigned short* Vthi = wsu + 4 * HSZ;
  unsigned short* Vtlo = wsu + 5 * HSZ;
  unsigned short* Ahi_ = wsu + 6 * HSZ;   // also XaHi (attention output plane)
  unsigned short* Alo_ = wsu + 7 * HSZ;   // also XaLo
  unsigned short* Wthi = wsu + 8 * HSZ;
  unsigned short* Wtlo = wsu + 8 * HSZ + WSZ;
  unsigned long long* Mb = (unsigned long long*)(wsu + 8 * HSZ + 2 * WSZ);

  const int n4 = (int)(HSZ / 4);

  mask_bits_kernel<<<BATCH * SLEN / 4, 256, 0, stream>>>(mask, Mb);

  // Q projection (softmax scale folded in, log2 domain)
  pack_act_kernel<<<1024, 256, 0, stream>>>(q, Ahi_, Alo_, n4);
  pack_wT_kernel<<<256, 256, 0, stream>>>(Wq, Wthi, Wtlo);
  gemm_sp_kernel<<<1024, 256, 0, stream>>>(Ahi_, Alo_, Wthi, Wtlo, bq, QSCALE, Qhi, Qlo, nullptr, 1);
  // K projection
  pack_act_kernel<<<1024, 256, 0, stream>>>(k, Ahi_, Alo_, n4);
  pack_wT_kernel<<<256, 256, 0, stream>>>(Wk, Wthi, Wtlo);
  gemm_sp_kernel<<<1024, 256, 0, stream>>>(Ahi_, Alo_, Wthi, Wtlo, bk, 1.0f, Khi, Klo, nullptr, 1);
  // V projection (transposed output)
  pack_act_kernel<<<1024, 256, 0, stream>>>(v, Ahi_, Alo_, n4);
  pack_wT_kernel<<<256, 256, 0, stream>>>(Wv, Wthi, Wtlo);
  gemm_sp_kernel<<<1024, 256, 0, stream>>>(Ahi_, Alo_, Wthi, Wtlo, bv, 1.0f, Vthi, Vtlo, nullptr, 2);

  // attention -> Xa planes (reuse A-plane buffers)
  attn_mfma_kernel<<<512, 512, 0, stream>>>(Qhi, Qlo, Khi, Klo, Vthi, Vtlo,
                                            Mb, Ahi_, Alo_);

  // output projection
  pack_wT_kernel<<<256, 256, 0, stream>>>(Wo, Wthi, Wtlo);
  gemm_sp_kernel<<<1024, 256, 0, stream>>>(Ahi_, Alo_, Wthi, Wtlo, bo, 1.0f, nullptr, nullptr, out, 0);
}

// Round 8
// 457.389 us; speedup vs baseline: 1.1182x; 1.0244x over previous
//
#include <hip/hip_runtime.h>
#include <hip/hip_bf16.h>
#include <math.h>

#define HIDDEN 1024
#define HEADS 16
#define DK 64
#define BATCH 2
#define SLEN 2048

typedef __attribute__((ext_vector_type(8))) short short8v;
typedef __attribute__((ext_vector_type(4))) float f32x4;

// --- truncation-based split: x = hi + lo + O(2^-17 |x|). 3-4 VALU ops. ---
__device__ __forceinline__ float bf_f(unsigned short h) {
  unsigned u = ((unsigned)h) << 16;
  return __builtin_bit_cast(float, u);
}
__device__ __forceinline__ void split_t(float x, unsigned short& hi,
                                        unsigned short& lo) {
  unsigned xu = __builtin_bit_cast(unsigned, x);
  float r = x - __builtin_bit_cast(float, xu & 0xffff0000u);
  hi = (unsigned short)(xu >> 16);
  lo = (unsigned short)(__builtin_bit_cast(unsigned, r) >> 16);
}
// packed (hi | lo<<16) in one u32 via a single v_perm
__device__ __forceinline__ unsigned pack_hl_t(float x) {
  unsigned xu = __builtin_bit_cast(unsigned, x);
  float r = x - __builtin_bit_cast(float, xu & 0xffff0000u);
  unsigned ru = __builtin_bit_cast(unsigned, r);
  return __builtin_amdgcn_perm(ru, xu, 0x07060302u);  // {x.b2,x.b3,r.b2,r.b3}
}

// unpack 8 packed u32 (hi|lo per element, k ascending) into hi or lo short8v
__device__ __forceinline__ short8v unpack8(const uint4& a0, const uint4& a1,
                                           unsigned sel) {
  uint4 r;
  r.x = __builtin_amdgcn_perm(a0.y, a0.x, sel);
  r.y = __builtin_amdgcn_perm(a0.w, a0.z, sel);
  r.z = __builtin_amdgcn_perm(a1.y, a1.x, sel);
  r.w = __builtin_amdgcn_perm(a1.w, a1.z, sel);
  return __builtin_bit_cast(short8v, r);
}
#define SEL_HI 0x05040100u
#define SEL_LO 0x07060302u

#define GLB_US(p) ((const __attribute__((address_space(1))) unsigned short*)(p))
#define LDS_US(p) ((__attribute__((address_space(3))) unsigned short*)(p))

#define QSCALE 0.18033688011112042f  /* 1/sqrt(64) * log2(e) */

// ---------------------------------------------------------------------------
// mask [B][1][S][S] int -> bitmask u64 per (row, 64-col tile). 1MB, L2-resident.
// ---------------------------------------------------------------------------
__global__ __launch_bounds__(256) void mask_bits_kernel(
    const int* __restrict__ mask, unsigned long long* __restrict__ Mb)
{
  const int row = blockIdx.x * 4 + (threadIdx.x >> 6);  // 0..B*S-1
  const int lane = threadIdx.x & 63;
  const int* mr = mask + (size_t)row * SLEN;
#pragma unroll
  for (int t = 0; t < 32; ++t) {
    int m = mr[t * 64 + lane];
    unsigned long long bits = __ballot(m != 0);
    if (lane == 0) Mb[(size_t)row * 32 + t] = bits;
  }
}

// ---------------------------------------------------------------------------
// pack fp32 -> separate bf16 hi/lo planes (truncation split)
// ---------------------------------------------------------------------------
__global__ __launch_bounds__(256) void pack_act_kernel(
    const float* __restrict__ src, unsigned short* __restrict__ hi,
    unsigned short* __restrict__ lo, int n4)
{
  int stride = gridDim.x * blockDim.x;
  for (int i = blockIdx.x * blockDim.x + threadIdx.x; i < n4; i += stride) {
    float4 v = ((const float4*)src)[i];
    ushort4 H, L;
    split_t(v.x, H.x, L.x); split_t(v.y, H.y, L.y);
    split_t(v.z, H.z, L.z); split_t(v.w, H.w, L.w);
    *(ushort4*)(hi + (size_t)i * 4) = H;
    *(ushort4*)(lo + (size_t)i * 4) = L;
  }
}

// ---------------------------------------------------------------------------
// pack + transpose weight: W[k][n] fp32 -> Wt hi/lo planes [n][k] bf16
// ---------------------------------------------------------------------------
__global__ __launch_bounds__(256) void pack_wT_kernel(
    const float* __restrict__ W, unsigned short* __restrict__ Whi,
    unsigned short* __restrict__ Wlo)
{
  __shared__ float T[64][65];
  const int t = threadIdx.x;
  const int bk = blockIdx.x >> 4, bn = blockIdx.x & 15;
#pragma unroll
  for (int i = 0; i < 4; ++i) {
    int k = (t >> 4) + i * 16, n = (t & 15) * 4;
    float4 v = *(const float4*)(W + (size_t)(bk * 64 + k) * HIDDEN + bn * 64 + n);
    T[k][n + 0] = v.x; T[k][n + 1] = v.y; T[k][n + 2] = v.z; T[k][n + 3] = v.w;
  }
  __syncthreads();
  const int nl = t & 63, kc = (t >> 6) * 16;
#pragma unroll
  for (int i = 0; i < 4; ++i) {
    ushort4 H, L;
    split_t(T[kc + i * 4 + 0][nl], H.x, L.x);
    split_t(T[kc + i * 4 + 1][nl], H.y, L.y);
    split_t(T[kc + i * 4 + 2][nl], H.z, L.z);
    split_t(T[kc + i * 4 + 3][nl], H.w, L.w);
    size_t base = (size_t)(bn * 64 + nl) * HIDDEN + bk * 64 + kc + i * 4;
    *(ushort4*)(Whi + base) = H;
    *(ushort4*)(Wlo + base) = L;
  }
}

// ---------------------------------------------------------------------------
// Split-precision bf16 MFMA GEMM v3. Block tile 128x128, grid 256 (1/CU),
// 4 waves (2x2), wave tile 64x64 = 4x4 16x16x32 frags. 16 ds_read_b128 feed
// 48 MFMAs per K-step (MFMA-bound: LDS ~1024 cyc < MFMA ~931+ cyc/CU vs the
// old 64x64-tile's 1536-cyc LDS wall). Double-buffered 2x32KB LDS; staging
// via global_load_lds (linear dest, source pre-swizzled with the read-side
// XOR (row>>1)&3). Accumulation order per element identical to v2.
// mode 0: Yf[m][n] fp32.  mode 1: Yhi/Ylo [bh][s][d].  mode 2: [bh*64+d][s].
// ---------------------------------------------------------------------------
__global__ __launch_bounds__(256) void gemm_sp_kernel(
    const unsigned short* __restrict__ Ahi, const unsigned short* __restrict__ Alo,
    const unsigned short* __restrict__ Bthi, const unsigned short* __restrict__ Btlo,
    const float* __restrict__ bias, float oscale,
    unsigned short* __restrict__ Yhi, unsigned short* __restrict__ Ylo,
    float* __restrict__ Yf, int mode)
{
  __shared__ __align__(16) unsigned short lds[2][4][128 * 32];  // 64KB

  const int tid = threadIdx.x;
  const int lb = (blockIdx.x & 7) * 32 + (blockIdx.x >> 3);  // XCD swizzle
  const int bm = lb >> 3;                 // 0..31
  const int bn = lb & 7;                  // 0..7  (fastest within XCD)
  const int m0 = bm * 128, n0 = bn * 128;
  const int w = tid >> 6, lane = tid & 63;
  const int wm = w >> 1, wn = w & 1;
  const int g = lane >> 4, qi = lane & 15;

  f32x4 acc[4][4];
#pragma unroll
  for (int mt = 0; mt < 4; ++mt)
#pragma unroll
    for (int nt = 0; nt < 4; ++nt) acc[mt][nt] = (f32x4){0.f, 0.f, 0.f, 0.f};

  auto stage = [&](int buf, int k0) {
#pragma unroll
    for (int i = 0; i < 2; ++i) {
      int c = tid + i * 256;              // chunk 0..511 per plane
      int r = c >> 2;                     // row 0..127
      int tc = (((c & 3) ^ ((r >> 1) & 3)) << 3);  // pre-swizzled src col
      size_t ga = (size_t)(m0 + r) * HIDDEN + k0 + tc;
      size_t gb = (size_t)(n0 + r) * HIDDEN + k0 + tc;
      int d = c * 8;                      // linear LDS dest (ushort)
      __builtin_amdgcn_global_load_lds(GLB_US(Ahi + ga), LDS_US(&lds[buf][0][d]), 16, 0, 0);
      __builtin_amdgcn_global_load_lds(GLB_US(Alo + ga), LDS_US(&lds[buf][1][d]), 16, 0, 0);
      __builtin_amdgcn_global_load_lds(GLB_US(Bthi + gb), LDS_US(&lds[buf][2][d]), 16, 0, 0);
      __builtin_amdgcn_global_load_lds(GLB_US(Btlo + gb), LDS_US(&lds[buf][3][d]), 16, 0, 0);
    }
  };

  auto compute = [&](int buf) {
    short8v a_h[4], a_l[4], b_h[4], b_l[4];
#pragma unroll
    for (int mt = 0; mt < 4; ++mt) {
      int R = wm * 64 + mt * 16 + qi;
      int cofs = R * 32 + ((g ^ ((R >> 1) & 3)) << 3);
      a_h[mt] = *(const short8v*)&lds[buf][0][cofs];
      a_l[mt] = *(const short8v*)&lds[buf][1][cofs];
    }
#pragma unroll
    for (int nt = 0; nt < 4; ++nt) {
      int R = wn * 64 + nt * 16 + qi;
      int cofs = R * 32 + ((g ^ ((R >> 1) & 3)) << 3);
      b_h[nt] = *(const short8v*)&lds[buf][2][cofs];
      b_l[nt] = *(const short8v*)&lds[buf][3][cofs];
    }
#pragma unroll
    for (int nt = 0; nt < 4; ++nt)
#pragma unroll
      for (int mt = 0; mt < 4; ++mt) {
        acc[mt][nt] = __builtin_amdgcn_mfma_f32_16x16x32_bf16(a_h[mt], b_h[nt], acc[mt][nt], 0, 0, 0);
        acc[mt][nt] = __builtin_amdgcn_mfma_f32_16x16x32_bf16(a_l[mt], b_h[nt], acc[mt][nt], 0, 0, 0);
        acc[mt][nt] = __builtin_amdgcn_mfma_f32_16x16x32_bf16(a_h[mt], b_l[nt], acc[mt][nt], 0, 0, 0);
      }
  };

  stage(0, 0);
  __syncthreads();
  for (int t = 0; t < 31; ++t) {
    stage((t + 1) & 1, (t + 1) * 32);  // async loads into other buffer
    compute(t & 1);
    __syncthreads();                   // drains vmcnt; protects buffer reuse
  }
  compute(1);

  // epilogue
#pragma unroll
  for (int nt = 0; nt < 4; ++nt) {
    int n = n0 + wn * 64 + nt * 16 + qi;
    float bv = bias[n];
#pragma unroll
    for (int mt = 0; mt < 4; ++mt) {
#pragma unroll
      for (int r = 0; r < 4; ++r) {
        int m = m0 + wm * 64 + mt * 16 + g * 4 + r;
        float val = (acc[mt][nt][r] + bv) * oscale;
        if (mode == 0) {
          Yf[(size_t)m * HIDDEN + n] = val;
        } else {
          int s = m & (SLEN - 1);
          int bh_ = (m >> 11) * HEADS + (n >> 6);
          int d = n & 63;
          unsigned short hi, lo;
          split_t(val, hi, lo);
          size_t base = (mode == 1) ? (((size_t)bh_ * SLEN + s) << 6) + d
                                    : ((size_t)(bh_ * DK + d)) * SLEN + s;
          Yhi[base] = hi;
          Ylo[base] = lo;
        }
      }
    }
  }
}

// ---------------------------------------------------------------------------
// MFMA flash attention v3: QBLK=128, 8 waves (512 thr), grid 512.
// Swapped QK^T, log2-domain softmax, u64 bitmask, defer-max THR=11.5.
// P (packed u32) per wave aliased into K region / dedicated 16KB. LDS 48KB.
// s_setprio(1) around MFMA clusters (T5: waves diverge between barriers).
// ---------------------------------------------------------------------------
__global__ __launch_bounds__(512) void attn_mfma_kernel(
    const unsigned short* __restrict__ Qhi, const unsigned short* __restrict__ Qlo,
    const unsigned short* __restrict__ Khi, const unsigned short* __restrict__ Klo,
    const unsigned short* __restrict__ Vthi, const unsigned short* __restrict__ Vtlo,
    const unsigned long long* __restrict__ Mb,
    unsigned short* __restrict__ XaHi, unsigned short* __restrict__ XaLo)
{
  __shared__ __align__(16) unsigned char smem[49152];
  unsigned short* Ks_hi = (unsigned short*)smem;             // [64][64] 8KB
  unsigned short* Ks_lo = (unsigned short*)(smem + 8192);
  unsigned short* Vs_hi = (unsigned short*)(smem + 16384);
  unsigned short* Vs_lo = (unsigned short*)(smem + 24576);

  const int tid = threadIdx.x;
  const int bx = blockIdx.x;
  const int lb = (bx & 7) * 64 + (bx >> 3);  // XCD swizzle (512 % 8 == 0)
  const int qt = lb & 15;                    // 16 q-tiles of 128
  const int bh = lb >> 4;
  const int b = bh >> 4, h = bh & 15;
  const int w = tid >> 6, lane = tid & 63;
  const int g = lane >> 4, qi = lane & 15;
  const int qbase = qt * 128 + w * 16;

  unsigned* Pw = (unsigned*)(w < 4 ? (smem + w * 4096)
                                   : (smem + 32768 + (w - 4) * 4096));

  short8v qh[2], ql[2];
  {
    const unsigned short* qr_hi = Qhi + ((size_t)bh * SLEN + qbase + qi) * DK;
    const unsigned short* qr_lo = Qlo + ((size_t)bh * SLEN + qbase + qi) * DK;
    qh[0] = *(const short8v*)(qr_hi + g * 8);
    qh[1] = *(const short8v*)(qr_hi + 32 + g * 8);
    ql[0] = *(const short8v*)(qr_lo + g * 8);
    ql[1] = *(const short8v*)(qr_lo + 32 + g * 8);
  }

  f32x4 o[4];
#pragma unroll
  for (int dt = 0; dt < 4; ++dt) o[dt] = (f32x4){0.f, 0.f, 0.f, 0.f};
  float m_run = -1e30f, l_run = 0.f;

  const unsigned long long* mrow = Mb + ((size_t)b * SLEN + qbase + qi) * 32;

  const int srow = tid >> 3;                         // 0..63
  const int scol = (((tid & 7) ^ (srow & 7)) << 3);  // pre-swizzled src (ushort)
  const int sdof = tid * 8;                          // linear dest (ushort)

  for (int k0 = 0; k0 < SLEN; k0 += 64) {
    __syncthreads();
    {
      size_t gk = ((size_t)bh * SLEN + k0 + srow) * 64 + scol;
      size_t gv = ((size_t)(bh * 64 + srow)) * SLEN + k0 + scol;
      __builtin_amdgcn_global_load_lds(GLB_US(Khi + gk), LDS_US(Ks_hi + sdof), 16, 0, 0);
      __builtin_amdgcn_global_load_lds(GLB_US(Klo + gk), LDS_US(Ks_lo + sdof), 16, 0, 0);
      __builtin_amdgcn_global_load_lds(GLB_US(Vthi + gv), LDS_US(Vs_hi + sdof), 16, 0, 0);
      __builtin_amdgcn_global_load_lds(GLB_US(Vtlo + gv), LDS_US(Vs_lo + sdof), 16, 0, 0);
    }
    __syncthreads();

    // QK^T swapped: S^T[k][q]; lane (g,qi) holds k = ks*16+g*4+r for q = qi
    f32x4 sf[4];
    __builtin_amdgcn_s_setprio(1);
#pragma unroll
    for (int ks = 0; ks < 4; ++ks) {
      int krow = ks * 16 + qi;
      int cswz = (krow & 7) << 3;
      short8v kh0 = *(const short8v*)&Ks_hi[krow * 64 + ((g * 8) ^ cswz)];
      short8v kh1 = *(const short8v*)&Ks_hi[krow * 64 + ((32 + g * 8) ^ cswz)];
      short8v kl0 = *(const short8v*)&Ks_lo[krow * 64 + ((g * 8) ^ cswz)];
      short8v kl1 = *(const short8v*)&Ks_lo[krow * 64 + ((32 + g * 8) ^ cswz)];
      f32x4 s = {0.f, 0.f, 0.f, 0.f};
      s = __builtin_amdgcn_mfma_f32_16x16x32_bf16(kh0, qh[0], s, 0, 0, 0);
      s = __builtin_amdgcn_mfma_f32_16x16x32_bf16(kh1, qh[1], s, 0, 0, 0);
      s = __builtin_amdgcn_mfma_f32_16x16x32_bf16(kh0, ql[0], s, 0, 0, 0);
      s = __builtin_amdgcn_mfma_f32_16x16x32_bf16(kh1, ql[1], s, 0, 0, 0);
      s = __builtin_amdgcn_mfma_f32_16x16x32_bf16(kl0, qh[0], s, 0, 0, 0);
      s = __builtin_amdgcn_mfma_f32_16x16x32_bf16(kl1, qh[1], s, 0, 0, 0);
      sf[ks] = s;
    }
    __builtin_amdgcn_s_setprio(0);
    __syncthreads();  // all waves done reading K region -> P may overwrite it

    // mask + per-lane softmax stats (log2 domain) for q-row qi
    unsigned long long mw = mrow[k0 >> 6];
    unsigned s0 = ((unsigned)mw) >> (g * 4);
    unsigned s1 = ((unsigned)(mw >> 32)) >> (g * 4);
    float sv[4][4];
    float rowmax = -INFINITY;
#pragma unroll
    for (int ks = 0; ks < 4; ++ks) {
      unsigned sel = (ks < 2) ? s0 : s1;
#pragma unroll
      for (int r = 0; r < 4; ++r) {
        float x = sf[ks][r];
        sv[ks][r] = ((sel >> (((ks & 1) << 4) + r)) & 1) ? x : -INFINITY;
        rowmax = fmaxf(rowmax, sv[ks][r]);
      }
    }
    rowmax = fmaxf(rowmax, __shfl_xor(rowmax, 16));
    rowmax = fmaxf(rowmax, __shfl_xor(rowmax, 32));

    if (__any(rowmax > m_run + 11.5f)) {  // defer-max, log2 domain
      float mnew = fmaxf(m_run, rowmax);
      float scale = exp2f(m_run - mnew);
      l_run *= scale;
#pragma unroll
      for (int r = 0; r < 4; ++r) {
        float sc = __shfl(scale, g * 4 + r);  // O rows are q = g*4+r
        o[0][r] *= sc; o[1][r] *= sc; o[2][r] *= sc; o[3][r] *= sc;
      }
      m_run = mnew;
    }

    // P = exp2(S - m), packed hi|lo, into [k][16] swizzled LDS
    float lsum = 0.f;
#pragma unroll
    for (int ks = 0; ks < 4; ++ks)
#pragma unroll
      for (int r = 0; r < 4; ++r) {
        float pv = exp2f(sv[ks][r] - m_run);
        lsum += pv;
        int k = ks * 16 + g * 4 + r;
        int wa = (k << 4) + qi;
        wa ^= ((wa >> 7) & 1) << 4;
        Pw[wa] = pack_hl_t(pv);
      }
    lsum += __shfl_xor(lsum, 16);
    lsum += __shfl_xor(lsum, 32);
    l_run += lsum;

    // PV: O += Phi*Vhi + Phi*Vlo + Plo*Vhi
#pragma unroll
    for (int kh = 0; kh < 2; ++kh) {
      unsigned u0, u1, u2, u3, u4, u5, u6, u7;
      {
        int kb = kh * 32 + g * 8;
        int ra;
        ra = ((kb + 0) << 4) + qi; ra ^= ((ra >> 7) & 1) << 4; u0 = Pw[ra];
        ra = ((kb + 1) << 4) + qi; ra ^= ((ra >> 7) & 1) << 4; u1 = Pw[ra];
        ra = ((kb + 2) << 4) + qi; ra ^= ((ra >> 7) & 1) << 4; u2 = Pw[ra];
        ra = ((kb + 3) << 4) + qi; ra ^= ((ra >> 7) & 1) << 4; u3 = Pw[ra];
        ra = ((kb + 4) << 4) + qi; ra ^= ((ra >> 7) & 1) << 4; u4 = Pw[ra];
        ra = ((kb + 5) << 4) + qi; ra ^= ((ra >> 7) & 1) << 4; u5 = Pw[ra];
        ra = ((kb + 6) << 4) + qi; ra ^= ((ra >> 7) & 1) << 4; u6 = Pw[ra];
        ra = ((kb + 7) << 4) + qi; ra ^= ((ra >> 7) & 1) << 4; u7 = Pw[ra];
      }
      uint4 a0 = {u0, u1, u2, u3}, a1 = {u4, u5, u6, u7};
      short8v phi = unpack8(a0, a1, SEL_HI);
      short8v plo = unpack8(a0, a1, SEL_LO);
      __builtin_amdgcn_s_setprio(1);
#pragma unroll
      for (int dt = 0; dt < 4; ++dt) {
        int drow = dt * 16 + qi;
        int vcol = (kh * 32 + g * 8) ^ ((drow & 7) << 3);
        short8v vh = *(const short8v*)&Vs_hi[drow * 64 + vcol];
        short8v vl = *(const short8v*)&Vs_lo[drow * 64 + vcol];
        o[dt] = __builtin_amdgcn_mfma_f32_16x16x32_bf16(phi, vh, o[dt], 0, 0, 0);
        o[dt] = __builtin_amdgcn_mfma_f32_16x16x32_bf16(phi, vl, o[dt], 0, 0, 0);
        o[dt] = __builtin_amdgcn_mfma_f32_16x16x32_bf16(plo, vh, o[dt], 0, 0, 0);
      }
      __builtin_amdgcn_s_setprio(0);
    }
  }

  // normalize + write Xa hi/lo planes [b*S+s][h*64+d]
#pragma unroll
  for (int r = 0; r < 4; ++r) {
    float lr = __shfl(l_run, g * 4 + r);
    float inv = lr > 0.f ? 1.f / lr : 0.f;
    size_t rowa = ((size_t)(b * SLEN) + qbase + g * 4 + r) * HIDDEN + h * DK;
#pragma unroll
    for (int dt = 0; dt < 4; ++dt) {
      float val = o[dt][r] * inv;
      unsigned short hi, lo;
      split_t(val, hi, lo);
      XaHi[rowa + dt * 16 + qi] = hi;
      XaLo[rowa + dt * 16 + qi] = lo;
    }
  }
}

// ---------------------------------------------------------------------------
extern "C" void kernel_launch(void* const* d_in, const int* in_sizes, int n_in,
                              void* d_out, int out_size, void* d_ws, size_t ws_size,
                              hipStream_t stream) {
  const float* q   = (const float*)d_in[0];
  const float* k   = (const float*)d_in[1];
  const float* v   = (const float*)d_in[2];
  const int*  mask = (const int*)d_in[3];
  const float* Wq  = (const float*)d_in[4];
  const float* bq  = (const float*)d_in[5];
  const float* Wk  = (const float*)d_in[6];
  const float* bk  = (const float*)d_in[7];
  const float* Wv  = (const float*)d_in[8];
  const float* bv  = (const float*)d_in[9];
  const float* Wo  = (const float*)d_in[10];
  const float* bo  = (const float*)d_in[11];
  float* out = (float*)d_out;

  const size_t HSZ = (size_t)BATCH * SLEN * HIDDEN;   // 4,194,304 elems
  const size_t WSZ = (size_t)HIDDEN * HIDDEN;         // 1,048,576 elems
  unsigned short* wsu = (unsigned short*)d_ws;
  unsigned short* Qhi = wsu;
  unsigned short* Qlo = wsu + HSZ;
  unsigned short* Khi = wsu + 2 * HSZ;
  unsigned short* Klo = wsu + 3 * HSZ;
  unsigned short* Vthi = wsu + 4 * HSZ;
  unsigned short* Vtlo = wsu + 5 * HSZ;
  unsigned short* Ahi_ = wsu + 6 * HSZ;   // also XaHi (attention output plane)
  unsigned short* Alo_ = wsu + 7 * HSZ;   // also XaLo
  unsigned short* Wthi = wsu + 8 * HSZ;
  unsigned short* Wtlo = wsu + 8 * HSZ + WSZ;
  unsigned long long* Mb = (unsigned long long*)(wsu + 8 * HSZ + 2 * WSZ);

  const int n4 = (int)(HSZ / 4);

  mask_bits_kernel<<<BATCH * SLEN / 4, 256, 0, stream>>>(mask, Mb);

  // Q projection (softmax scale folded in, log2 domain)
  pack_act_kernel<<<1024, 256, 0, stream>>>(q, Ahi_, Alo_, n4);
  pack_wT_kernel<<<256, 256, 0, stream>>>(Wq, Wthi, Wtlo);
  gemm_sp_kernel<<<256, 256, 0, stream>>>(Ahi_, Alo_, Wthi, Wtlo, bq, QSCALE, Qhi, Qlo, nullptr, 1);
  // K projection
  pack_act_kernel<<<1024, 256, 0, stream>>>(k, Ahi_, Alo_, n4);
  pack_wT_kernel<<<256, 256, 0, stream>>>(Wk, Wthi, Wtlo);
  gemm_sp_kernel<<<256, 256, 0, stream>>>(Ahi_, Alo_, Wthi, Wtlo, bk, 1.0f, Khi, Klo, nullptr, 1);
  // V projection (transposed output)
  pack_act_kernel<<<1024, 256, 0, stream>>>(v, Ahi_, Alo_, n4);
  pack_wT_kernel<<<256, 256, 0, stream>>>(Wv, Wthi, Wtlo);
  gemm_sp_kernel<<<256, 256, 0, stream>>>(Ahi_, Alo_, Wthi, Wtlo, bv, 1.0f, Vthi, Vtlo, nullptr, 2);

  // attention -> Xa planes (reuse A-plane buffers)
  attn_mfma_kernel<<<512, 512, 0, stream>>>(Qhi, Qlo, Khi, Klo, Vthi, Vtlo,
                                            Mb, Ahi_, Alo_);

  // output projection
  pack_wT_kernel<<<256, 256, 0, stream>>>(Wo, Wthi, Wtlo);
  gemm_sp_kernel<<<256, 256, 0, stream>>>(Ahi_, Alo_, Wthi, Wtlo, bo, 1.0f, nullptr, nullptr, out, 0);
}